// Round 16
// baseline (2552.780 us; speedup 1.0000x reference)
//
#include <hip/hip_runtime.h>

#define B_ 8
#define H_ 16
#define L_ 1024
#define DH_ 64
#define DM_ 1024
#define NP_ 2047
#define NP2_ 2048
#define SCALE_ 0.125f

#define PS_ 1032   // P bf16 row stride (shorts)
#define HS_ 260    // hist f32 row stride (8-pass, 256 + pad)

typedef __attribute__((ext_vector_type(8))) short bf16x8;
typedef __attribute__((ext_vector_type(4))) float f32x4;

__device__ __forceinline__ unsigned short f2bf(float x) {
    union { float f; unsigned int u; } v; v.f = x;
    return (unsigned short)((v.u + 0x7FFFu + ((v.u >> 16) & 1u)) >> 16);
}
__device__ __forceinline__ float bf2f(unsigned short b) {
    union { unsigned int u; float f; } v; v.u = ((unsigned int)b) << 16;
    return v.f;
}

// ---------------- projection GEMM: Y = X @ W^T (fp32 VALU core) — proven R8/R14 ----------------
// MODE 0: head-split hi/lo bf16 (q, k); MODE 1: fp32 flat (Wo); MODE 2: head-split transposed bf16 (v)
template <int MODE>
__global__ __launch_bounds__(256) void proj_gemm(const float* __restrict__ X,
                                                 const float* __restrict__ W,
                                                 float* __restrict__ Yf,
                                                 unsigned short* __restrict__ Y0,
                                                 unsigned short* __restrict__ Y1)
{
    __shared__ __align__(16) float As[16][68];
    __shared__ __align__(16) float Bs[16][68];
    const int t   = threadIdx.x;
    const int tm  = t & 15;
    const int tn  = t >> 4;
    const int row0 = blockIdx.x * 64;
    const int col0 = blockIdx.y * 64;
    const int lr = t >> 2;
    const int lc = (t & 3) * 4;

    float acc[4][4];
#pragma unroll
    for (int i = 0; i < 4; ++i)
#pragma unroll
        for (int j = 0; j < 4; ++j) acc[i][j] = 0.f;

    for (int k0 = 0; k0 < DM_; k0 += 16) {
        float4 av = *(const float4*)(X + (size_t)(row0 + lr) * DM_ + k0 + lc);
        float4 wv = *(const float4*)(W + (size_t)(col0 + lr) * DM_ + k0 + lc);
        __syncthreads();
        As[lc + 0][lr] = av.x; As[lc + 1][lr] = av.y;
        As[lc + 2][lr] = av.z; As[lc + 3][lr] = av.w;
        Bs[lc + 0][lr] = wv.x; Bs[lc + 1][lr] = wv.y;
        Bs[lc + 2][lr] = wv.z; Bs[lc + 3][lr] = wv.w;
        __syncthreads();
#pragma unroll
        for (int kk = 0; kk < 16; ++kk) {
            float4 a  = *(const float4*)&As[kk][tm * 4];
            float4 w4 = *(const float4*)&Bs[kk][tn * 4];
            acc[0][0] = fmaf(a.x, w4.x, acc[0][0]);
            acc[0][1] = fmaf(a.x, w4.y, acc[0][1]);
            acc[0][2] = fmaf(a.x, w4.z, acc[0][2]);
            acc[0][3] = fmaf(a.x, w4.w, acc[0][3]);
            acc[1][0] = fmaf(a.y, w4.x, acc[1][0]);
            acc[1][1] = fmaf(a.y, w4.y, acc[1][1]);
            acc[1][2] = fmaf(a.y, w4.z, acc[1][2]);
            acc[1][3] = fmaf(a.y, w4.w, acc[1][3]);
            acc[2][0] = fmaf(a.z, w4.x, acc[2][0]);
            acc[2][1] = fmaf(a.z, w4.y, acc[2][1]);
            acc[2][2] = fmaf(a.z, w4.z, acc[2][2]);
            acc[2][3] = fmaf(a.z, w4.w, acc[2][3]);
            acc[3][0] = fmaf(a.w, w4.x, acc[3][0]);
            acc[3][1] = fmaf(a.w, w4.y, acc[3][1]);
            acc[3][2] = fmaf(a.w, w4.z, acc[3][2]);
            acc[3][3] = fmaf(a.w, w4.w, acc[3][3]);
        }
    }

    const int h = blockIdx.y;
#pragma unroll
    for (int i = 0; i < 4; ++i) {
        const int row = row0 + tm * 4 + i;
        if (MODE == 1) {
            float4 r = make_float4(acc[i][0], acc[i][1], acc[i][2], acc[i][3]);
            *(float4*)(Yf + (size_t)row * DM_ + col0 + tn * 4) = r;
        } else {
            const int bb = row >> 10;
            const int l  = row & 1023;
            if (MODE == 0) {
                ushort4 hi4, lo4;
                unsigned short* hp = (unsigned short*)&hi4;
                unsigned short* lp = (unsigned short*)&lo4;
#pragma unroll
                for (int j = 0; j < 4; ++j) {
                    unsigned short hb = f2bf(acc[i][j]);
                    hp[j] = hb;
                    lp[j] = f2bf(acc[i][j] - bf2f(hb));
                }
                const size_t base = (((size_t)bb * H_ + h) * L_ + l) * DH_ + tn * 4;
                *(ushort4*)(Y0 + base) = hi4;
                *(ushort4*)(Y1 + base) = lo4;
            } else {  // MODE 2: transposed bf16
#pragma unroll
                for (int j = 0; j < 4; ++j) {
                    const int d = tn * 4 + j;
                    Y0[(((size_t)bb * H_ + h) * DH_ + d) * L_ + l] = f2bf(acc[i][j]);
                }
            }
        }
    }
}

// ---------------- rel_k bf16 + rel_v transpose prep (known-good) ----------------
__global__ __launch_bounds__(256) void prep_rel(const float* __restrict__ rk,
                                                const float* __restrict__ rv,
                                                unsigned short* __restrict__ rk_hi,
                                                unsigned short* __restrict__ rv_t)
{
    const int idx = blockIdx.x * 256 + threadIdx.x;   // 0 .. 2048*64-1
    const int p = idx >> 6;
    const int d = idx & 63;
    float xk = (p < NP_) ? rk[(size_t)p * DH_ + d] : 0.f;
    rk_hi[idx] = f2bf(xk);
    float xv = (p < NP_) ? rv[(size_t)p * DH_ + d] : 0.f;
    rv_t[(size_t)d * NP2_ + p] = f2bf(xv);
}

// ---------------- MFMA Shaw attention v7 — R14 + 8-pass hist => 3 blocks/CU ----------------
// vs R14 (passing): hist shrunk to 256-wide x 8 passes (regionB 33->16.6 KB, LDS ~51 KB),
// launch_bounds (512,6). Same scatter/MFMA work; only pass-loop overhead grows.
__global__ __launch_bounds__(512, 6) void shaw_attn_mfma(
    const unsigned short* __restrict__ qh, const unsigned short* __restrict__ ql,
    const unsigned short* __restrict__ kh, const unsigned short* __restrict__ kl,
    const unsigned short* __restrict__ vt, const int* __restrict__ ridx,
    const unsigned short* __restrict__ rkh, const unsigned short* __restrict__ rvt,
    float* __restrict__ out)
{
    __shared__ __align__(16) unsigned char regionA[16 * PS_ * 2];  // 33,024 B: qrel8 -> Pu
    __shared__ __align__(16) unsigned char regionB[16 * HS_ * 4];  // 16,640 B: hist -> red
    __shared__ float pmax[16][8];
    __shared__ float psum[16][8];

    char*           qrel8 = (char*)regionA;              // [2048][16]
    unsigned short* Pu    = (unsigned short*)regionA;    // [16][PS_] (after qrel dead)
    float*          hist  = (float*)regionB;             // [16][HS_]
    float*          red   = (float*)regionB;             // [8][16][20] = 10,240 B (after hist dead)

    const int t    = threadIdx.x;
    const int w    = t >> 6;
    const int lane = t & 63;
    const int mrow = lane & 15;
    const int grp  = lane >> 4;
    const int i0   = blockIdx.x * 16;
    const int h    = blockIdx.y;
    const int b    = blockIdx.z;
    const size_t bh = (size_t)b * H_ + h;

    const unsigned short* qhp = qh + bh * (size_t)(L_ * DH_);
    const unsigned short* qlp = ql + bh * (size_t)(L_ * DH_);
    const unsigned short* khp = kh + bh * (size_t)(L_ * DH_);
    const unsigned short* klp = kl + bh * (size_t)(L_ * DH_);
    const unsigned short* vtp = vt + bh * (size_t)(DH_ * L_);

    // Q A-fragments
    bf16x8 qAh[2], qAl[2];
#pragma unroll
    for (int s = 0; s < 2; ++s) {
        const size_t off = (size_t)(i0 + mrow) * DH_ + s * 32 + grp * 8;
        qAh[s] = *(const bf16x8*)(qhp + off);
        qAl[s] = *(const bf16x8*)(qlp + off);
    }

    // ---- Phase 1: qrel int8 (x128) ----
    {
        const unsigned short* rb = rkh + (size_t)(w * 256 + mrow) * DH_ + grp * 8;
#pragma unroll 4
        for (int tt = 0; tt < 16; ++tt) {
            bf16x8 Bh0 = *(const bf16x8*)(rb + tt * 1024);
            bf16x8 Bh1 = *(const bf16x8*)(rb + tt * 1024 + 32);
            f32x4 c = {0.f, 0.f, 0.f, 0.f};
            c = __builtin_amdgcn_mfma_f32_16x16x32_bf16(qAh[0], Bh0, c, 0, 0, 0);
            c = __builtin_amdgcn_mfma_f32_16x16x32_bf16(qAh[1], Bh1, c, 0, 0, 0);
            const int pcol = (w * 16 + tt) * 16 + mrow;
            unsigned int pk = 0;
#pragma unroll
            for (int r = 0; r < 4; ++r) {
                int qi = (int)rintf(c[r] * 128.f);
                qi = qi > 127 ? 127 : (qi < -127 ? -127 : qi);
                pk |= ((unsigned int)(qi & 0xff)) << (8 * r);
            }
            *(unsigned int*)(qrel8 + pcol * 16 + grp * 4) = pk;
        }
    }
    __syncthreads();   // qrel ready

    // ---- Phase 2a: content scores (split-bf16 QK^T) ----
    float sc[8][4];
    {
        const unsigned short* kbh = khp + (size_t)(w * 128 + mrow) * DH_ + grp * 8;
        const unsigned short* kbl = klp + (size_t)(w * 128 + mrow) * DH_ + grp * 8;
#pragma unroll 2
        for (int tt = 0; tt < 8; ++tt) {
            bf16x8 Bh0 = *(const bf16x8*)(kbh + tt * 1024);
            bf16x8 Bh1 = *(const bf16x8*)(kbh + tt * 1024 + 32);
            bf16x8 Bl0 = *(const bf16x8*)(kbl + tt * 1024);
            bf16x8 Bl1 = *(const bf16x8*)(kbl + tt * 1024 + 32);
            f32x4 c = {0.f, 0.f, 0.f, 0.f};
            c = __builtin_amdgcn_mfma_f32_16x16x32_bf16(qAh[0], Bh0, c, 0, 0, 0);
            c = __builtin_amdgcn_mfma_f32_16x16x32_bf16(qAh[1], Bh1, c, 0, 0, 0);
            c = __builtin_amdgcn_mfma_f32_16x16x32_bf16(qAh[0], Bl0, c, 0, 0, 0);
            c = __builtin_amdgcn_mfma_f32_16x16x32_bf16(qAh[1], Bl1, c, 0, 0, 0);
            c = __builtin_amdgcn_mfma_f32_16x16x32_bf16(qAl[0], Bh0, c, 0, 0, 0);
            c = __builtin_amdgcn_mfma_f32_16x16x32_bf16(qAl[1], Bh1, c, 0, 0, 0);
#pragma unroll
            for (int r = 0; r < 4; ++r) sc[tt][r] = c[r] * SCALE_;
        }
    }

    // ---- Phase 2b: rel gather ----
#pragma unroll
    for (int tt = 0; tt < 8; ++tt) {
        const int jcol = (w * 8 + tt) * 16 + mrow;
#pragma unroll
        for (int r = 0; r < 4; ++r) {
            const int pidx = ridx[(size_t)(i0 + grp * 4 + r) * L_ + jcol];
            sc[tt][r] = fmaf((float)qrel8[pidx * 16 + grp * 4 + r], SCALE_ / 128.f, sc[tt][r]);
        }
    }

    // ---- Phase 3: softmax ----
    float mx[4];
#pragma unroll
    for (int r = 0; r < 4; ++r) {
        float m = sc[0][r];
#pragma unroll
        for (int tt = 1; tt < 8; ++tt) m = fmaxf(m, sc[tt][r]);
#pragma unroll
        for (int off = 1; off < 16; off <<= 1) m = fmaxf(m, __shfl_xor(m, off));
        mx[r] = m;
    }
    {
        const float wv0 = (mrow == 0) ? mx[0] : (mrow == 1) ? mx[1] : (mrow == 2) ? mx[2] : mx[3];
        if (mrow < 4) pmax[grp * 4 + mrow][w] = wv0;
    }
    __syncthreads();   // pmax ready; last qrel8 read done before Pu overwrite below

    float gm[4];
#pragma unroll
    for (int r = 0; r < 4; ++r) {
        const int rr = grp * 4 + r;
        float m = pmax[rr][0];
#pragma unroll
        for (int u = 1; u < 8; ++u) m = fmaxf(m, pmax[rr][u]);
        gm[r] = m;
    }
    float sm[4] = {0.f, 0.f, 0.f, 0.f};
#pragma unroll
    for (int tt = 0; tt < 8; ++tt) {
        const int jcol = (w * 8 + tt) * 16 + mrow;
#pragma unroll
        for (int r = 0; r < 4; ++r) {
            const float e = __expf(sc[tt][r] - gm[r]);
            sm[r] += e;
            Pu[(grp * 4 + r) * PS_ + jcol] = f2bf(e);   // into dead qrel region
        }
    }
#pragma unroll
    for (int r = 0; r < 4; ++r) {
#pragma unroll
        for (int off = 1; off < 16; off <<= 1) sm[r] += __shfl_xor(sm[r], off);
    }
    {
        const float sv0 = (mrow == 0) ? sm[0] : (mrow == 1) ? sm[1] : (mrow == 2) ? sm[2] : sm[3];
        if (mrow < 4) psum[grp * 4 + mrow][w] = sv0;
    }
    __syncthreads();   // Pu + psum ready

    // ---- Phase 4: O1 = P @ V (wave task (n, khalf)) ----
    const int n = w & 3;
    const int khalf = w >> 2;
    f32x4 acc = {0.f, 0.f, 0.f, 0.f};
    {
        const unsigned short* vcol = vtp + (size_t)(n * 16 + mrow) * L_ + khalf * 512 + grp * 8;
#pragma unroll 4
        for (int s = 0; s < 16; ++s) {
            bf16x8 a  = *(const bf16x8*)(Pu + mrow * PS_ + khalf * 512 + s * 32 + grp * 8);
            bf16x8 bb = *(const bf16x8*)(vcol + s * 32);
            acc = __builtin_amdgcn_mfma_f32_16x16x32_bf16(a, bb, acc, 0, 0, 0);
        }
    }

    // ---- Phase 5: 8 hist passes of 256 positions (hist in its own region; Pu stays live) ----
    for (int pass = 0; pass < 8; ++pass) {
        {
            float4* h4 = (float4*)hist;
            const float4 z4 = make_float4(0.f, 0.f, 0.f, 0.f);
            for (int z = t; z < (16 * HS_) / 4; z += 512) h4[z] = z4;
        }
        __syncthreads();
        // scatter: each thread scatters its own 32 (row, j) P-entries (LDS reads of own writes)
#pragma unroll
        for (int tt = 0; tt < 8; ++tt) {
            const int jcol = (w * 8 + tt) * 16 + mrow;
#pragma unroll
            for (int r = 0; r < 4; ++r) {
                const int rr = grp * 4 + r;
                const int pidx = ridx[(size_t)(i0 + rr) * L_ + jcol];
                if ((pidx >> 8) == pass)
                    atomicAdd(&hist[rr * HS_ + (pidx & 255)], bf2f(Pu[rr * PS_ + jcol]));
            }
        }
        __syncthreads();
        // O2 += hist(256-wide) @ rel_v: per (n, khalf) wave, 4 k-tiles of 32
        const unsigned short* rvcol =
            rvt + (size_t)(n * 16 + mrow) * NP2_ + pass * 256 + khalf * 128 + grp * 8;
#pragma unroll
        for (int s = 0; s < 4; ++s) {
            const int kb = khalf * 128 + s * 32;
            const f32x4* hp = (const f32x4*)&hist[mrow * HS_ + kb + grp * 8];
            f32x4 h0 = hp[0], h1 = hp[1];
            bf16x8 a;
#pragma unroll
            for (int e = 0; e < 4; ++e) { a[e] = (short)f2bf(h0[e]); a[e + 4] = (short)f2bf(h1[e]); }
            bf16x8 bb = *(const bf16x8*)(rvcol + s * 32);
            acc = __builtin_amdgcn_mfma_f32_16x16x32_bf16(a, bb, acc, 0, 0, 0);
        }
        __syncthreads();   // readers done -> next zero / red alias safe
    }

    // ---- Phase 6: khalf reduce + normalize + fp32 store ----
#pragma unroll
    for (int r = 0; r < 4; ++r) red[w * 320 + (grp * 4 + r) * 20 + mrow] = acc[r];
    __syncthreads();
    if (w < 4) {
#pragma unroll
        for (int r = 0; r < 4; ++r) {
            const int rr = grp * 4 + r;
            float o = red[w * 320 + rr * 20 + mrow] + red[(w + 4) * 320 + rr * 20 + mrow];
            float ssum = 0.f;
#pragma unroll
            for (int u = 0; u < 8; ++u) ssum += psum[rr][u];
            out[((size_t)b * L_ + i0 + rr) * DM_ + h * DH_ + w * 16 + mrow] = o / ssum;
        }
    }
}

extern "C" void kernel_launch(void* const* d_in, const int* in_sizes, int n_in,
                              void* d_out, int out_size, void* d_ws, size_t ws_size,
                              hipStream_t stream)
{
    const float* x    = (const float*)d_in[0];
    const int*   ridx = (const int*)  d_in[1];
    const float* Wq   = (const float*)d_in[2];
    const float* Wk   = (const float*)d_in[3];
    const float* Wv   = (const float*)d_in[4];
    const float* Wo   = (const float*)d_in[5];
    const float* rk   = (const float*)d_in[6];
    const float* rv   = (const float*)d_in[7];
    float* out = (float*)d_out;

    // R8/R14's proven workspace plan: 117,964,800 B; every buffer single-writer.
    const size_t NQ = (size_t)B_ * H_ * L_ * DH_;      // 8,388,608
    float* attn = (float*)d_ws;                        // NQ f32
    unsigned short* u = (unsigned short*)(attn + NQ);
    unsigned short* qh = u;            u += NQ;
    unsigned short* ql = u;            u += NQ;
    unsigned short* kh = u;            u += NQ;
    unsigned short* kl = u;            u += NQ;
    unsigned short* vt = u;            u += NQ;
    unsigned short* rkh = u;           u += (size_t)NP2_ * DH_;
    unsigned short* rvt = u;           u += (size_t)NP2_ * DH_;

    dim3 gthr(256);
    dim3 ggrid((B_ * L_) / 64, DM_ / 64);   // (128, 16)

    prep_rel<<<dim3((NP2_ * DH_) / 256), gthr, 0, stream>>>(rk, rv, rkh, rvt);
    proj_gemm<0><<<ggrid, gthr, 0, stream>>>(x, Wq, nullptr, qh, ql);
    proj_gemm<0><<<ggrid, gthr, 0, stream>>>(x, Wk, nullptr, kh, kl);
    proj_gemm<2><<<ggrid, gthr, 0, stream>>>(x, Wv, nullptr, vt, nullptr);

    shaw_attn_mfma<<<dim3(L_ / 16, H_, B_), dim3(512), 0, stream>>>(
        qh, ql, kh, kl, vt, ridx, rkh, rvt, attn);

    proj_gemm<1><<<ggrid, gthr, 0, stream>>>(attn, Wo, out, nullptr, nullptr);
}

// Round 17
// 2265.021 us; speedup vs baseline: 1.1270x; 1.1270x over previous
//
#include <hip/hip_runtime.h>

#define B_ 8
#define H_ 16
#define L_ 1024
#define DH_ 64
#define DM_ 1024
#define NP_ 2047
#define NP2_ 2048
#define SCALE_ 0.125f

#define PS_ 1032   // P bf16 row stride (shorts)
#define HS_ 260    // hist f32 row stride (8-pass, 256 + pad)

typedef __attribute__((ext_vector_type(8))) short bf16x8;
typedef __attribute__((ext_vector_type(4))) float f32x4;

__device__ __forceinline__ unsigned short f2bf(float x) {
    union { float f; unsigned int u; } v; v.f = x;
    return (unsigned short)((v.u + 0x7FFFu + ((v.u >> 16) & 1u)) >> 16);
}
__device__ __forceinline__ float bf2f(unsigned short b) {
    union { unsigned int u; float f; } v; v.u = ((unsigned int)b) << 16;
    return v.f;
}

// ---------------- projection GEMM: Y = X @ W^T (fp32 VALU core) — proven R8/R14 ----------------
// MODE 0: head-split hi/lo bf16 (q, k); MODE 1: fp32 flat (Wo); MODE 2: head-split transposed bf16 (v)
template <int MODE>
__global__ __launch_bounds__(256) void proj_gemm(const float* __restrict__ X,
                                                 const float* __restrict__ W,
                                                 float* __restrict__ Yf,
                                                 unsigned short* __restrict__ Y0,
                                                 unsigned short* __restrict__ Y1)
{
    __shared__ __align__(16) float As[16][68];
    __shared__ __align__(16) float Bs[16][68];
    const int t   = threadIdx.x;
    const int tm  = t & 15;
    const int tn  = t >> 4;
    const int row0 = blockIdx.x * 64;
    const int col0 = blockIdx.y * 64;
    const int lr = t >> 2;
    const int lc = (t & 3) * 4;

    float acc[4][4];
#pragma unroll
    for (int i = 0; i < 4; ++i)
#pragma unroll
        for (int j = 0; j < 4; ++j) acc[i][j] = 0.f;

    for (int k0 = 0; k0 < DM_; k0 += 16) {
        float4 av = *(const float4*)(X + (size_t)(row0 + lr) * DM_ + k0 + lc);
        float4 wv = *(const float4*)(W + (size_t)(col0 + lr) * DM_ + k0 + lc);
        __syncthreads();
        As[lc + 0][lr] = av.x; As[lc + 1][lr] = av.y;
        As[lc + 2][lr] = av.z; As[lc + 3][lr] = av.w;
        Bs[lc + 0][lr] = wv.x; Bs[lc + 1][lr] = wv.y;
        Bs[lc + 2][lr] = wv.z; Bs[lc + 3][lr] = wv.w;
        __syncthreads();
#pragma unroll
        for (int kk = 0; kk < 16; ++kk) {
            float4 a  = *(const float4*)&As[kk][tm * 4];
            float4 w4 = *(const float4*)&Bs[kk][tn * 4];
            acc[0][0] = fmaf(a.x, w4.x, acc[0][0]);
            acc[0][1] = fmaf(a.x, w4.y, acc[0][1]);
            acc[0][2] = fmaf(a.x, w4.z, acc[0][2]);
            acc[0][3] = fmaf(a.x, w4.w, acc[0][3]);
            acc[1][0] = fmaf(a.y, w4.x, acc[1][0]);
            acc[1][1] = fmaf(a.y, w4.y, acc[1][1]);
            acc[1][2] = fmaf(a.y, w4.z, acc[1][2]);
            acc[1][3] = fmaf(a.y, w4.w, acc[1][3]);
            acc[2][0] = fmaf(a.z, w4.x, acc[2][0]);
            acc[2][1] = fmaf(a.z, w4.y, acc[2][1]);
            acc[2][2] = fmaf(a.z, w4.z, acc[2][2]);
            acc[2][3] = fmaf(a.z, w4.w, acc[2][3]);
            acc[3][0] = fmaf(a.w, w4.x, acc[3][0]);
            acc[3][1] = fmaf(a.w, w4.y, acc[3][1]);
            acc[3][2] = fmaf(a.w, w4.z, acc[3][2]);
            acc[3][3] = fmaf(a.w, w4.w, acc[3][3]);
        }
    }

    const int h = blockIdx.y;
#pragma unroll
    for (int i = 0; i < 4; ++i) {
        const int row = row0 + tm * 4 + i;
        if (MODE == 1) {
            float4 r = make_float4(acc[i][0], acc[i][1], acc[i][2], acc[i][3]);
            *(float4*)(Yf + (size_t)row * DM_ + col0 + tn * 4) = r;
        } else {
            const int bb = row >> 10;
            const int l  = row & 1023;
            if (MODE == 0) {
                ushort4 hi4, lo4;
                unsigned short* hp = (unsigned short*)&hi4;
                unsigned short* lp = (unsigned short*)&lo4;
#pragma unroll
                for (int j = 0; j < 4; ++j) {
                    unsigned short hb = f2bf(acc[i][j]);
                    hp[j] = hb;
                    lp[j] = f2bf(acc[i][j] - bf2f(hb));
                }
                const size_t base = (((size_t)bb * H_ + h) * L_ + l) * DH_ + tn * 4;
                *(ushort4*)(Y0 + base) = hi4;
                *(ushort4*)(Y1 + base) = lo4;
            } else {  // MODE 2: transposed bf16
#pragma unroll
                for (int j = 0; j < 4; ++j) {
                    const int d = tn * 4 + j;
                    Y0[(((size_t)bb * H_ + h) * DH_ + d) * L_ + l] = f2bf(acc[i][j]);
                }
            }
        }
    }
}

// ---------------- rel_k bf16 + rel_v transpose prep (known-good) ----------------
__global__ __launch_bounds__(256) void prep_rel(const float* __restrict__ rk,
                                                const float* __restrict__ rv,
                                                unsigned short* __restrict__ rk_hi,
                                                unsigned short* __restrict__ rv_t)
{
    const int idx = blockIdx.x * 256 + threadIdx.x;   // 0 .. 2048*64-1
    const int p = idx >> 6;
    const int d = idx & 63;
    float xk = (p < NP_) ? rk[(size_t)p * DH_ + d] : 0.f;
    rk_hi[idx] = f2bf(xk);
    float xv = (p < NP_) ? rv[(size_t)p * DH_ + d] : 0.f;
    rv_t[(size_t)d * NP2_ + p] = f2bf(xv);
}

// ---------------- MFMA Shaw attention v8 — 8-pass hist (51 KB LDS) + (512,4) no-spill bounds ----------------
// R16's kernel with R14's launch bound: LDS alone admits 3 blocks/CU; VGPR stays at
// the natural ~56 (no forced spill). Combines R14's no-spill with R16's occupancy.
__global__ __launch_bounds__(512, 4) void shaw_attn_mfma(
    const unsigned short* __restrict__ qh, const unsigned short* __restrict__ ql,
    const unsigned short* __restrict__ kh, const unsigned short* __restrict__ kl,
    const unsigned short* __restrict__ vt, const int* __restrict__ ridx,
    const unsigned short* __restrict__ rkh, const unsigned short* __restrict__ rvt,
    float* __restrict__ out)
{
    __shared__ __align__(16) unsigned char regionA[16 * PS_ * 2];  // 33,024 B: qrel8 -> Pu
    __shared__ __align__(16) unsigned char regionB[16 * HS_ * 4];  // 16,640 B: hist -> red
    __shared__ float pmax[16][8];
    __shared__ float psum[16][8];

    char*           qrel8 = (char*)regionA;              // [2048][16]
    unsigned short* Pu    = (unsigned short*)regionA;    // [16][PS_] (after qrel dead)
    float*          hist  = (float*)regionB;             // [16][HS_]
    float*          red   = (float*)regionB;             // [8][16][20] = 10,240 B (after hist dead)

    const int t    = threadIdx.x;
    const int w    = t >> 6;
    const int lane = t & 63;
    const int mrow = lane & 15;
    const int grp  = lane >> 4;
    const int i0   = blockIdx.x * 16;
    const int h    = blockIdx.y;
    const int b    = blockIdx.z;
    const size_t bh = (size_t)b * H_ + h;

    const unsigned short* qhp = qh + bh * (size_t)(L_ * DH_);
    const unsigned short* qlp = ql + bh * (size_t)(L_ * DH_);
    const unsigned short* khp = kh + bh * (size_t)(L_ * DH_);
    const unsigned short* klp = kl + bh * (size_t)(L_ * DH_);
    const unsigned short* vtp = vt + bh * (size_t)(DH_ * L_);

    // Q A-fragments
    bf16x8 qAh[2], qAl[2];
#pragma unroll
    for (int s = 0; s < 2; ++s) {
        const size_t off = (size_t)(i0 + mrow) * DH_ + s * 32 + grp * 8;
        qAh[s] = *(const bf16x8*)(qhp + off);
        qAl[s] = *(const bf16x8*)(qlp + off);
    }

    // ---- Phase 1: qrel int8 (x128) ----
    {
        const unsigned short* rb = rkh + (size_t)(w * 256 + mrow) * DH_ + grp * 8;
#pragma unroll 4
        for (int tt = 0; tt < 16; ++tt) {
            bf16x8 Bh0 = *(const bf16x8*)(rb + tt * 1024);
            bf16x8 Bh1 = *(const bf16x8*)(rb + tt * 1024 + 32);
            f32x4 c = {0.f, 0.f, 0.f, 0.f};
            c = __builtin_amdgcn_mfma_f32_16x16x32_bf16(qAh[0], Bh0, c, 0, 0, 0);
            c = __builtin_amdgcn_mfma_f32_16x16x32_bf16(qAh[1], Bh1, c, 0, 0, 0);
            const int pcol = (w * 16 + tt) * 16 + mrow;
            unsigned int pk = 0;
#pragma unroll
            for (int r = 0; r < 4; ++r) {
                int qi = (int)rintf(c[r] * 128.f);
                qi = qi > 127 ? 127 : (qi < -127 ? -127 : qi);
                pk |= ((unsigned int)(qi & 0xff)) << (8 * r);
            }
            *(unsigned int*)(qrel8 + pcol * 16 + grp * 4) = pk;
        }
    }
    __syncthreads();   // qrel ready

    // ---- Phase 2a: content scores (split-bf16 QK^T) ----
    float sc[8][4];
    {
        const unsigned short* kbh = khp + (size_t)(w * 128 + mrow) * DH_ + grp * 8;
        const unsigned short* kbl = klp + (size_t)(w * 128 + mrow) * DH_ + grp * 8;
#pragma unroll 2
        for (int tt = 0; tt < 8; ++tt) {
            bf16x8 Bh0 = *(const bf16x8*)(kbh + tt * 1024);
            bf16x8 Bh1 = *(const bf16x8*)(kbh + tt * 1024 + 32);
            bf16x8 Bl0 = *(const bf16x8*)(kbl + tt * 1024);
            bf16x8 Bl1 = *(const bf16x8*)(kbl + tt * 1024 + 32);
            f32x4 c = {0.f, 0.f, 0.f, 0.f};
            c = __builtin_amdgcn_mfma_f32_16x16x32_bf16(qAh[0], Bh0, c, 0, 0, 0);
            c = __builtin_amdgcn_mfma_f32_16x16x32_bf16(qAh[1], Bh1, c, 0, 0, 0);
            c = __builtin_amdgcn_mfma_f32_16x16x32_bf16(qAh[0], Bl0, c, 0, 0, 0);
            c = __builtin_amdgcn_mfma_f32_16x16x32_bf16(qAh[1], Bl1, c, 0, 0, 0);
            c = __builtin_amdgcn_mfma_f32_16x16x32_bf16(qAl[0], Bh0, c, 0, 0, 0);
            c = __builtin_amdgcn_mfma_f32_16x16x32_bf16(qAl[1], Bh1, c, 0, 0, 0);
#pragma unroll
            for (int r = 0; r < 4; ++r) sc[tt][r] = c[r] * SCALE_;
        }
    }

    // ---- Phase 2b: rel gather ----
#pragma unroll
    for (int tt = 0; tt < 8; ++tt) {
        const int jcol = (w * 8 + tt) * 16 + mrow;
#pragma unroll
        for (int r = 0; r < 4; ++r) {
            const int pidx = ridx[(size_t)(i0 + grp * 4 + r) * L_ + jcol];
            sc[tt][r] = fmaf((float)qrel8[pidx * 16 + grp * 4 + r], SCALE_ / 128.f, sc[tt][r]);
        }
    }

    // ---- Phase 3: softmax ----
    float mx[4];
#pragma unroll
    for (int r = 0; r < 4; ++r) {
        float m = sc[0][r];
#pragma unroll
        for (int tt = 1; tt < 8; ++tt) m = fmaxf(m, sc[tt][r]);
#pragma unroll
        for (int off = 1; off < 16; off <<= 1) m = fmaxf(m, __shfl_xor(m, off));
        mx[r] = m;
    }
    {
        const float wv0 = (mrow == 0) ? mx[0] : (mrow == 1) ? mx[1] : (mrow == 2) ? mx[2] : mx[3];
        if (mrow < 4) pmax[grp * 4 + mrow][w] = wv0;
    }
    __syncthreads();   // pmax ready; last qrel8 read done before Pu overwrite below

    float gm[4];
#pragma unroll
    for (int r = 0; r < 4; ++r) {
        const int rr = grp * 4 + r;
        float m = pmax[rr][0];
#pragma unroll
        for (int u = 1; u < 8; ++u) m = fmaxf(m, pmax[rr][u]);
        gm[r] = m;
    }
    float sm[4] = {0.f, 0.f, 0.f, 0.f};
#pragma unroll
    for (int tt = 0; tt < 8; ++tt) {
        const int jcol = (w * 8 + tt) * 16 + mrow;
#pragma unroll
        for (int r = 0; r < 4; ++r) {
            const float e = __expf(sc[tt][r] - gm[r]);
            sm[r] += e;
            Pu[(grp * 4 + r) * PS_ + jcol] = f2bf(e);   // into dead qrel region
        }
    }
#pragma unroll
    for (int r = 0; r < 4; ++r) {
#pragma unroll
        for (int off = 1; off < 16; off <<= 1) sm[r] += __shfl_xor(sm[r], off);
    }
    {
        const float sv0 = (mrow == 0) ? sm[0] : (mrow == 1) ? sm[1] : (mrow == 2) ? sm[2] : sm[3];
        if (mrow < 4) psum[grp * 4 + mrow][w] = sv0;
    }
    __syncthreads();   // Pu + psum ready

    // ---- Phase 4: O1 = P @ V (wave task (n, khalf)) ----
    const int n = w & 3;
    const int khalf = w >> 2;
    f32x4 acc = {0.f, 0.f, 0.f, 0.f};
    {
        const unsigned short* vcol = vtp + (size_t)(n * 16 + mrow) * L_ + khalf * 512 + grp * 8;
#pragma unroll 4
        for (int s = 0; s < 16; ++s) {
            bf16x8 a  = *(const bf16x8*)(Pu + mrow * PS_ + khalf * 512 + s * 32 + grp * 8);
            bf16x8 bb = *(const bf16x8*)(vcol + s * 32);
            acc = __builtin_amdgcn_mfma_f32_16x16x32_bf16(a, bb, acc, 0, 0, 0);
        }
    }

    // ---- Phase 5: 8 hist passes of 256 positions (hist in its own region; Pu stays live) ----
    for (int pass = 0; pass < 8; ++pass) {
        {
            float4* h4 = (float4*)hist;
            const float4 z4 = make_float4(0.f, 0.f, 0.f, 0.f);
            for (int z = t; z < (16 * HS_) / 4; z += 512) h4[z] = z4;
        }
        __syncthreads();
        // scatter: each thread scatters its own 32 (row, j) P-entries (LDS reads of own writes)
#pragma unroll
        for (int tt = 0; tt < 8; ++tt) {
            const int jcol = (w * 8 + tt) * 16 + mrow;
#pragma unroll
            for (int r = 0; r < 4; ++r) {
                const int rr = grp * 4 + r;
                const int pidx = ridx[(size_t)(i0 + rr) * L_ + jcol];
                if ((pidx >> 8) == pass)
                    atomicAdd(&hist[rr * HS_ + (pidx & 255)], bf2f(Pu[rr * PS_ + jcol]));
            }
        }
        __syncthreads();
        // O2 += hist(256-wide) @ rel_v: per (n, khalf) wave, 4 k-tiles of 32
        const unsigned short* rvcol =
            rvt + (size_t)(n * 16 + mrow) * NP2_ + pass * 256 + khalf * 128 + grp * 8;
#pragma unroll
        for (int s = 0; s < 4; ++s) {
            const int kb = khalf * 128 + s * 32;
            const f32x4* hp = (const f32x4*)&hist[mrow * HS_ + kb + grp * 8];
            f32x4 h0 = hp[0], h1 = hp[1];
            bf16x8 a;
#pragma unroll
            for (int e = 0; e < 4; ++e) { a[e] = (short)f2bf(h0[e]); a[e + 4] = (short)f2bf(h1[e]); }
            bf16x8 bb = *(const bf16x8*)(rvcol + s * 32);
            acc = __builtin_amdgcn_mfma_f32_16x16x32_bf16(a, bb, acc, 0, 0, 0);
        }
        __syncthreads();   // readers done -> next zero / red alias safe
    }

    // ---- Phase 6: khalf reduce + normalize + fp32 store ----
#pragma unroll
    for (int r = 0; r < 4; ++r) red[w * 320 + (grp * 4 + r) * 20 + mrow] = acc[r];
    __syncthreads();
    if (w < 4) {
#pragma unroll
        for (int r = 0; r < 4; ++r) {
            const int rr = grp * 4 + r;
            float o = red[w * 320 + rr * 20 + mrow] + red[(w + 4) * 320 + rr * 20 + mrow];
            float ssum = 0.f;
#pragma unroll
            for (int u = 0; u < 8; ++u) ssum += psum[rr][u];
            out[((size_t)b * L_ + i0 + rr) * DM_ + h * DH_ + w * 16 + mrow] = o / ssum;
        }
    }
}

extern "C" void kernel_launch(void* const* d_in, const int* in_sizes, int n_in,
                              void* d_out, int out_size, void* d_ws, size_t ws_size,
                              hipStream_t stream)
{
    const float* x    = (const float*)d_in[0];
    const int*   ridx = (const int*)  d_in[1];
    const float* Wq   = (const float*)d_in[2];
    const float* Wk   = (const float*)d_in[3];
    const float* Wv   = (const float*)d_in[4];
    const float* Wo   = (const float*)d_in[5];
    const float* rk   = (const float*)d_in[6];
    const float* rv   = (const float*)d_in[7];
    float* out = (float*)d_out;

    // R8/R14's proven workspace plan: 117,964,800 B; every buffer single-writer.
    const size_t NQ = (size_t)B_ * H_ * L_ * DH_;      // 8,388,608
    float* attn = (float*)d_ws;                        // NQ f32
    unsigned short* u = (unsigned short*)(attn + NQ);
    unsigned short* qh = u;            u += NQ;
    unsigned short* ql = u;            u += NQ;
    unsigned short* kh = u;            u += NQ;
    unsigned short* kl = u;            u += NQ;
    unsigned short* vt = u;            u += NQ;
    unsigned short* rkh = u;           u += (size_t)NP2_ * DH_;
    unsigned short* rvt = u;           u += (size_t)NP2_ * DH_;

    dim3 gthr(256);
    dim3 ggrid((B_ * L_) / 64, DM_ / 64);   // (128, 16)

    prep_rel<<<dim3((NP2_ * DH_) / 256), gthr, 0, stream>>>(rk, rv, rkh, rvt);
    proj_gemm<0><<<ggrid, gthr, 0, stream>>>(x, Wq, nullptr, qh, ql);
    proj_gemm<0><<<ggrid, gthr, 0, stream>>>(x, Wk, nullptr, kh, kl);
    proj_gemm<2><<<ggrid, gthr, 0, stream>>>(x, Wv, nullptr, vt, nullptr);

    shaw_attn_mfma<<<dim3(L_ / 16, H_, B_), dim3(512), 0, stream>>>(
        qh, ql, kh, kl, vt, ridx, rkh, rvt, attn);

    proj_gemm<1><<<ggrid, gthr, 0, stream>>>(attn, Wo, out, nullptr, nullptr);
}

// Round 18
// 2147.636 us; speedup vs baseline: 1.1886x; 1.0547x over previous
//
#include <hip/hip_runtime.h>

#define B_ 8
#define H_ 16
#define L_ 1024
#define DH_ 64
#define DM_ 1024
#define NP_ 2047
#define NP2_ 2048
#define SCALE_ 0.125f

#define PS_ 1032   // P bf16 row stride (shorts)
#define HS_ 260    // hist f32 row stride (8-pass, 256 + pad)

typedef __attribute__((ext_vector_type(8))) short bf16x8;
typedef __attribute__((ext_vector_type(4))) float f32x4;

__device__ __forceinline__ unsigned short f2bf(float x) {
    union { float f; unsigned int u; } v; v.f = x;
    return (unsigned short)((v.u + 0x7FFFu + ((v.u >> 16) & 1u)) >> 16);
}
__device__ __forceinline__ float bf2f(unsigned short b) {
    union { unsigned int u; float f; } v; v.u = ((unsigned int)b) << 16;
    return v.f;
}

// ---------------- projection GEMM v2: 128x128 tile, 8x8 micro-tile (LDS-BW fix) ----------------
// Y = X @ W^T, fp32 VALU core. 256 threads. Micro-tile rows {tm*4..+3, 64+tm*4..+3}, cols tn*8..+7.
// MODE 0: head-split hi/lo bf16 (q, k); MODE 1: fp32 flat (Wo); MODE 2: head-split transposed bf16 (v)
template <int MODE>
__global__ __launch_bounds__(256) void proj_gemm(const float* __restrict__ X,
                                                 const float* __restrict__ W,
                                                 float* __restrict__ Yf,
                                                 unsigned short* __restrict__ Y0,
                                                 unsigned short* __restrict__ Y1)
{
    __shared__ __align__(16) float As[16][132];
    __shared__ __align__(16) float Bs[16][132];
    const int t   = threadIdx.x;
    const int tm  = t & 15;         // row group
    const int tn  = t >> 4;         // col group 0..15
    const int row0 = blockIdx.x * 128;
    const int col0 = blockIdx.y * 128;
    const int lr  = t >> 1;         // staging row 0..127
    const int lc  = (t & 1) * 8;    // staging k-offset 0 or 8

    float acc[8][8];
#pragma unroll
    for (int i = 0; i < 8; ++i)
#pragma unroll
        for (int j = 0; j < 8; ++j) acc[i][j] = 0.f;

    // register double-buffered staging
    float4 xa, xb, wa, wb;
    const float* xp = X + (size_t)(row0 + lr) * DM_ + lc;
    const float* wp = W + (size_t)(col0 + lr) * DM_ + lc;
    xa = *(const float4*)(xp);     xb = *(const float4*)(xp + 4);
    wa = *(const float4*)(wp);     wb = *(const float4*)(wp + 4);

    for (int k0 = 0; k0 < DM_; k0 += 16) {
        __syncthreads();   // previous tile fully consumed
        As[lc + 0][lr] = xa.x; As[lc + 1][lr] = xa.y; As[lc + 2][lr] = xa.z; As[lc + 3][lr] = xa.w;
        As[lc + 4][lr] = xb.x; As[lc + 5][lr] = xb.y; As[lc + 6][lr] = xb.z; As[lc + 7][lr] = xb.w;
        Bs[lc + 0][lr] = wa.x; Bs[lc + 1][lr] = wa.y; Bs[lc + 2][lr] = wa.z; Bs[lc + 3][lr] = wa.w;
        Bs[lc + 4][lr] = wb.x; Bs[lc + 5][lr] = wb.y; Bs[lc + 6][lr] = wb.z; Bs[lc + 7][lr] = wb.w;
        __syncthreads();
        if (k0 + 16 < DM_) {
            xa = *(const float4*)(xp + k0 + 16);  xb = *(const float4*)(xp + k0 + 20);
            wa = *(const float4*)(wp + k0 + 16);  wb = *(const float4*)(wp + k0 + 20);
        }
#pragma unroll
        for (int kk = 0; kk < 16; ++kk) {
            float4 a0 = *(const float4*)&As[kk][tm * 4];
            float4 a1 = *(const float4*)&As[kk][64 + tm * 4];
            float4 b0 = *(const float4*)&Bs[kk][tn * 8];
            float4 b1 = *(const float4*)&Bs[kk][tn * 8 + 4];
            const float av[8] = {a0.x, a0.y, a0.z, a0.w, a1.x, a1.y, a1.z, a1.w};
            const float bv[8] = {b0.x, b0.y, b0.z, b0.w, b1.x, b1.y, b1.z, b1.w};
#pragma unroll
            for (int i = 0; i < 8; ++i)
#pragma unroll
                for (int j = 0; j < 8; ++j)
                    acc[i][j] = fmaf(av[i], bv[j], acc[i][j]);
        }
    }

    const int bidx = row0 >> 10;                 // 128-row tiles never straddle a batch
    const int hbase = blockIdx.y * 2 + (tn >> 3);  // head for MODE 0/2
    const int dbase = (tn & 7) * 8;                // dh base for MODE 0/2

    if constexpr (MODE == 1) {
#pragma unroll
        for (int i = 0; i < 8; ++i) {
            const int row = row0 + ((i < 4) ? (tm * 4 + i) : (64 + tm * 4 + i - 4));
            *(float4*)(Yf + (size_t)row * DM_ + col0 + tn * 8)     = make_float4(acc[i][0], acc[i][1], acc[i][2], acc[i][3]);
            *(float4*)(Yf + (size_t)row * DM_ + col0 + tn * 8 + 4) = make_float4(acc[i][4], acc[i][5], acc[i][6], acc[i][7]);
        }
    }
    if constexpr (MODE == 0) {
#pragma unroll
        for (int i = 0; i < 8; ++i) {
            const int row = row0 + ((i < 4) ? (tm * 4 + i) : (64 + tm * 4 + i - 4));
            const int l = row & 1023;
            const size_t base = (((size_t)bidx * H_ + hbase) * L_ + l) * DH_ + dbase;
#pragma unroll
            for (int jh = 0; jh < 2; ++jh) {
                ushort4 hi4, lo4;
                unsigned short* hp = (unsigned short*)&hi4;
                unsigned short* lp = (unsigned short*)&lo4;
#pragma unroll
                for (int j = 0; j < 4; ++j) {
                    const float y = acc[i][jh * 4 + j];
                    unsigned short hb = f2bf(y);
                    hp[j] = hb;
                    lp[j] = f2bf(y - bf2f(hb));
                }
                *(ushort4*)(Y0 + base + jh * 4) = hi4;
                *(ushort4*)(Y1 + base + jh * 4) = lo4;
            }
        }
    }
    if constexpr (MODE == 2) {
        // transposed store straight from registers: for each d, 4 consecutive l's -> ushort4
#pragma unroll
        for (int j = 0; j < 8; ++j) {
            const int d = dbase + j;
            const size_t cb = ((size_t)(bidx * H_ + hbase) * DH_ + d) * L_;
#pragma unroll
            for (int half = 0; half < 2; ++half) {
                const int l0 = (row0 & 1023) + half * 64 + tm * 4;
                ushort4 v4;
                unsigned short* vp = (unsigned short*)&v4;
#pragma unroll
                for (int i = 0; i < 4; ++i) vp[i] = f2bf(acc[half * 4 + i][j]);
                *(ushort4*)(Y0 + cb + l0) = v4;
            }
        }
    }
}

// ---------------- rel_k bf16 + rel_v transpose prep (known-good) ----------------
__global__ __launch_bounds__(256) void prep_rel(const float* __restrict__ rk,
                                                const float* __restrict__ rv,
                                                unsigned short* __restrict__ rk_hi,
                                                unsigned short* __restrict__ rv_t)
{
    const int idx = blockIdx.x * 256 + threadIdx.x;   // 0 .. 2048*64-1
    const int p = idx >> 6;
    const int d = idx & 63;
    float xk = (p < NP_) ? rk[(size_t)p * DH_ + d] : 0.f;
    rk_hi[idx] = f2bf(xk);
    float xv = (p < NP_) ? rv[(size_t)p * DH_ + d] : 0.f;
    rv_t[(size_t)d * NP2_ + p] = f2bf(xv);
}

// ---------------- MFMA Shaw attention v8 — R17 VERBATIM (best: 2265 µs) ----------------
__global__ __launch_bounds__(512, 4) void shaw_attn_mfma(
    const unsigned short* __restrict__ qh, const unsigned short* __restrict__ ql,
    const unsigned short* __restrict__ kh, const unsigned short* __restrict__ kl,
    const unsigned short* __restrict__ vt, const int* __restrict__ ridx,
    const unsigned short* __restrict__ rkh, const unsigned short* __restrict__ rvt,
    float* __restrict__ out)
{
    __shared__ __align__(16) unsigned char regionA[16 * PS_ * 2];  // 33,024 B: qrel8 -> Pu
    __shared__ __align__(16) unsigned char regionB[16 * HS_ * 4];  // 16,640 B: hist -> red
    __shared__ float pmax[16][8];
    __shared__ float psum[16][8];

    char*           qrel8 = (char*)regionA;              // [2048][16]
    unsigned short* Pu    = (unsigned short*)regionA;    // [16][PS_] (after qrel dead)
    float*          hist  = (float*)regionB;             // [16][HS_]
    float*          red   = (float*)regionB;             // [8][16][20] = 10,240 B (after hist dead)

    const int t    = threadIdx.x;
    const int w    = t >> 6;
    const int lane = t & 63;
    const int mrow = lane & 15;
    const int grp  = lane >> 4;
    const int i0   = blockIdx.x * 16;
    const int h    = blockIdx.y;
    const int b    = blockIdx.z;
    const size_t bh = (size_t)b * H_ + h;

    const unsigned short* qhp = qh + bh * (size_t)(L_ * DH_);
    const unsigned short* qlp = ql + bh * (size_t)(L_ * DH_);
    const unsigned short* khp = kh + bh * (size_t)(L_ * DH_);
    const unsigned short* klp = kl + bh * (size_t)(L_ * DH_);
    const unsigned short* vtp = vt + bh * (size_t)(DH_ * L_);

    // Q A-fragments
    bf16x8 qAh[2], qAl[2];
#pragma unroll
    for (int s = 0; s < 2; ++s) {
        const size_t off = (size_t)(i0 + mrow) * DH_ + s * 32 + grp * 8;
        qAh[s] = *(const bf16x8*)(qhp + off);
        qAl[s] = *(const bf16x8*)(qlp + off);
    }

    // ---- Phase 1: qrel int8 (x128) ----
    {
        const unsigned short* rb = rkh + (size_t)(w * 256 + mrow) * DH_ + grp * 8;
#pragma unroll 4
        for (int tt = 0; tt < 16; ++tt) {
            bf16x8 Bh0 = *(const bf16x8*)(rb + tt * 1024);
            bf16x8 Bh1 = *(const bf16x8*)(rb + tt * 1024 + 32);
            f32x4 c = {0.f, 0.f, 0.f, 0.f};
            c = __builtin_amdgcn_mfma_f32_16x16x32_bf16(qAh[0], Bh0, c, 0, 0, 0);
            c = __builtin_amdgcn_mfma_f32_16x16x32_bf16(qAh[1], Bh1, c, 0, 0, 0);
            const int pcol = (w * 16 + tt) * 16 + mrow;
            unsigned int pk = 0;
#pragma unroll
            for (int r = 0; r < 4; ++r) {
                int qi = (int)rintf(c[r] * 128.f);
                qi = qi > 127 ? 127 : (qi < -127 ? -127 : qi);
                pk |= ((unsigned int)(qi & 0xff)) << (8 * r);
            }
            *(unsigned int*)(qrel8 + pcol * 16 + grp * 4) = pk;
        }
    }
    __syncthreads();   // qrel ready

    // ---- Phase 2a: content scores (split-bf16 QK^T) ----
    float sc[8][4];
    {
        const unsigned short* kbh = khp + (size_t)(w * 128 + mrow) * DH_ + grp * 8;
        const unsigned short* kbl = klp + (size_t)(w * 128 + mrow) * DH_ + grp * 8;
#pragma unroll 2
        for (int tt = 0; tt < 8; ++tt) {
            bf16x8 Bh0 = *(const bf16x8*)(kbh + tt * 1024);
            bf16x8 Bh1 = *(const bf16x8*)(kbh + tt * 1024 + 32);
            bf16x8 Bl0 = *(const bf16x8*)(kbl + tt * 1024);
            bf16x8 Bl1 = *(const bf16x8*)(kbl + tt * 1024 + 32);
            f32x4 c = {0.f, 0.f, 0.f, 0.f};
            c = __builtin_amdgcn_mfma_f32_16x16x32_bf16(qAh[0], Bh0, c, 0, 0, 0);
            c = __builtin_amdgcn_mfma_f32_16x16x32_bf16(qAh[1], Bh1, c, 0, 0, 0);
            c = __builtin_amdgcn_mfma_f32_16x16x32_bf16(qAh[0], Bl0, c, 0, 0, 0);
            c = __builtin_amdgcn_mfma_f32_16x16x32_bf16(qAh[1], Bl1, c, 0, 0, 0);
            c = __builtin_amdgcn_mfma_f32_16x16x32_bf16(qAl[0], Bh0, c, 0, 0, 0);
            c = __builtin_amdgcn_mfma_f32_16x16x32_bf16(qAl[1], Bh1, c, 0, 0, 0);
#pragma unroll
            for (int r = 0; r < 4; ++r) sc[tt][r] = c[r] * SCALE_;
        }
    }

    // ---- Phase 2b: rel gather ----
#pragma unroll
    for (int tt = 0; tt < 8; ++tt) {
        const int jcol = (w * 8 + tt) * 16 + mrow;
#pragma unroll
        for (int r = 0; r < 4; ++r) {
            const int pidx = ridx[(size_t)(i0 + grp * 4 + r) * L_ + jcol];
            sc[tt][r] = fmaf((float)qrel8[pidx * 16 + grp * 4 + r], SCALE_ / 128.f, sc[tt][r]);
        }
    }

    // ---- Phase 3: softmax ----
    float mx[4];
#pragma unroll
    for (int r = 0; r < 4; ++r) {
        float m = sc[0][r];
#pragma unroll
        for (int tt = 1; tt < 8; ++tt) m = fmaxf(m, sc[tt][r]);
#pragma unroll
        for (int off = 1; off < 16; off <<= 1) m = fmaxf(m, __shfl_xor(m, off));
        mx[r] = m;
    }
    {
        const float wv0 = (mrow == 0) ? mx[0] : (mrow == 1) ? mx[1] : (mrow == 2) ? mx[2] : mx[3];
        if (mrow < 4) pmax[grp * 4 + mrow][w] = wv0;
    }
    __syncthreads();   // pmax ready; last qrel8 read done before Pu overwrite below

    float gm[4];
#pragma unroll
    for (int r = 0; r < 4; ++r) {
        const int rr = grp * 4 + r;
        float m = pmax[rr][0];
#pragma unroll
        for (int u = 1; u < 8; ++u) m = fmaxf(m, pmax[rr][u]);
        gm[r] = m;
    }
    float sm[4] = {0.f, 0.f, 0.f, 0.f};
#pragma unroll
    for (int tt = 0; tt < 8; ++tt) {
        const int jcol = (w * 8 + tt) * 16 + mrow;
#pragma unroll
        for (int r = 0; r < 4; ++r) {
            const float e = __expf(sc[tt][r] - gm[r]);
            sm[r] += e;
            Pu[(grp * 4 + r) * PS_ + jcol] = f2bf(e);   // into dead qrel region
        }
    }
#pragma unroll
    for (int r = 0; r < 4; ++r) {
#pragma unroll
        for (int off = 1; off < 16; off <<= 1) sm[r] += __shfl_xor(sm[r], off);
    }
    {
        const float sv0 = (mrow == 0) ? sm[0] : (mrow == 1) ? sm[1] : (mrow == 2) ? sm[2] : sm[3];
        if (mrow < 4) psum[grp * 4 + mrow][w] = sv0;
    }
    __syncthreads();   // Pu + psum ready

    // ---- Phase 4: O1 = P @ V (wave task (n, khalf)) ----
    const int n = w & 3;
    const int khalf = w >> 2;
    f32x4 acc = {0.f, 0.f, 0.f, 0.f};
    {
        const unsigned short* vcol = vtp + (size_t)(n * 16 + mrow) * L_ + khalf * 512 + grp * 8;
#pragma unroll 4
        for (int s = 0; s < 16; ++s) {
            bf16x8 a  = *(const bf16x8*)(Pu + mrow * PS_ + khalf * 512 + s * 32 + grp * 8);
            bf16x8 bb = *(const bf16x8*)(vcol + s * 32);
            acc = __builtin_amdgcn_mfma_f32_16x16x32_bf16(a, bb, acc, 0, 0, 0);
        }
    }

    // ---- Phase 5: 8 hist passes of 256 positions (hist in its own region; Pu stays live) ----
    for (int pass = 0; pass < 8; ++pass) {
        {
            float4* h4 = (float4*)hist;
            const float4 z4 = make_float4(0.f, 0.f, 0.f, 0.f);
            for (int z = t; z < (16 * HS_) / 4; z += 512) h4[z] = z4;
        }
        __syncthreads();
        // scatter: each thread scatters its own 32 (row, j) P-entries (LDS reads of own writes)
#pragma unroll
        for (int tt = 0; tt < 8; ++tt) {
            const int jcol = (w * 8 + tt) * 16 + mrow;
#pragma unroll
            for (int r = 0; r < 4; ++r) {
                const int rr = grp * 4 + r;
                const int pidx = ridx[(size_t)(i0 + rr) * L_ + jcol];
                if ((pidx >> 8) == pass)
                    atomicAdd(&hist[rr * HS_ + (pidx & 255)], bf2f(Pu[rr * PS_ + jcol]));
            }
        }
        __syncthreads();
        // O2 += hist(256-wide) @ rel_v: per (n, khalf) wave, 4 k-tiles of 32
        const unsigned short* rvcol =
            rvt + (size_t)(n * 16 + mrow) * NP2_ + pass * 256 + khalf * 128 + grp * 8;
#pragma unroll
        for (int s = 0; s < 4; ++s) {
            const int kb = khalf * 128 + s * 32;
            const f32x4* hp = (const f32x4*)&hist[mrow * HS_ + kb + grp * 8];
            f32x4 h0 = hp[0], h1 = hp[1];
            bf16x8 a;
#pragma unroll
            for (int e = 0; e < 4; ++e) { a[e] = (short)f2bf(h0[e]); a[e + 4] = (short)f2bf(h1[e]); }
            bf16x8 bb = *(const bf16x8*)(rvcol + s * 32);
            acc = __builtin_amdgcn_mfma_f32_16x16x32_bf16(a, bb, acc, 0, 0, 0);
        }
        __syncthreads();   // readers done -> next zero / red alias safe
    }

    // ---- Phase 6: khalf reduce + normalize + fp32 store ----
#pragma unroll
    for (int r = 0; r < 4; ++r) red[w * 320 + (grp * 4 + r) * 20 + mrow] = acc[r];
    __syncthreads();
    if (w < 4) {
#pragma unroll
        for (int r = 0; r < 4; ++r) {
            const int rr = grp * 4 + r;
            float o = red[w * 320 + rr * 20 + mrow] + red[(w + 4) * 320 + rr * 20 + mrow];
            float ssum = 0.f;
#pragma unroll
            for (int u = 0; u < 8; ++u) ssum += psum[rr][u];
            out[((size_t)b * L_ + i0 + rr) * DM_ + h * DH_ + w * 16 + mrow] = o / ssum;
        }
    }
}

extern "C" void kernel_launch(void* const* d_in, const int* in_sizes, int n_in,
                              void* d_out, int out_size, void* d_ws, size_t ws_size,
                              hipStream_t stream)
{
    const float* x    = (const float*)d_in[0];
    const int*   ridx = (const int*)  d_in[1];
    const float* Wq   = (const float*)d_in[2];
    const float* Wk   = (const float*)d_in[3];
    const float* Wv   = (const float*)d_in[4];
    const float* Wo   = (const float*)d_in[5];
    const float* rk   = (const float*)d_in[6];
    const float* rv   = (const float*)d_in[7];
    float* out = (float*)d_out;

    // R8/R14/R17's proven workspace plan: 117,964,800 B; every buffer single-writer.
    const size_t NQ = (size_t)B_ * H_ * L_ * DH_;      // 8,388,608
    float* attn = (float*)d_ws;                        // NQ f32
    unsigned short* u = (unsigned short*)(attn + NQ);
    unsigned short* qh = u;            u += NQ;
    unsigned short* ql = u;            u += NQ;
    unsigned short* kh = u;            u += NQ;
    unsigned short* kl = u;            u += NQ;
    unsigned short* vt = u;            u += NQ;
    unsigned short* rkh = u;           u += (size_t)NP2_ * DH_;
    unsigned short* rvt = u;           u += (size_t)NP2_ * DH_;

    dim3 gthr(256);
    dim3 ggrid((B_ * L_) / 128, DM_ / 128);   // (64, 8) — 128x128 tiles

    prep_rel<<<dim3((NP2_ * DH_) / 256), gthr, 0, stream>>>(rk, rv, rkh, rvt);
    proj_gemm<0><<<ggrid, gthr, 0, stream>>>(x, Wq, nullptr, qh, ql);
    proj_gemm<0><<<ggrid, gthr, 0, stream>>>(x, Wk, nullptr, kh, kl);
    proj_gemm<2><<<ggrid, gthr, 0, stream>>>(x, Wv, nullptr, vt, nullptr);

    shaw_attn_mfma<<<dim3(L_ / 16, H_, B_), dim3(512), 0, stream>>>(
        qh, ql, kh, kl, vt, ridx, rkh, rvt, attn);

    proj_gemm<1><<<ggrid, gthr, 0, stream>>>(attn, Wo, out, nullptr, nullptr);
}

// Round 19
// 2139.989 us; speedup vs baseline: 1.1929x; 1.0036x over previous
//
#include <hip/hip_runtime.h>

#define B_ 8
#define H_ 16
#define L_ 1024
#define DH_ 64
#define DM_ 1024
#define NP_ 2047
#define NP2_ 2048
#define SCALE_ 0.125f

#define PS_ 1032   // P bf16 row stride (shorts)
#define HS_ 260    // hist f32 row stride (8-pass, 256 + pad)

typedef __attribute__((ext_vector_type(8))) short bf16x8;
typedef __attribute__((ext_vector_type(4))) float f32x4;

__device__ __forceinline__ unsigned short f2bf(float x) {
    union { float f; unsigned int u; } v; v.f = x;
    return (unsigned short)((v.u + 0x7FFFu + ((v.u >> 16) & 1u)) >> 16);
}
__device__ __forceinline__ float bf2f(unsigned short b) {
    union { unsigned int u; float f; } v; v.u = ((unsigned int)b) << 16;
    return v.f;
}

// ---------------- projection GEMM v2: 128x128 tile, 8x8 micro-tile ----------------
// Y = X @ W^T, fp32 VALU core. 256 threads. Micro-tile rows {tm*4..+3, 64+tm*4..+3}, cols tn*8..+7.
// MODE 0: head-split hi/lo bf16 (q, k); MODE 1: fp32 flat (Wo); MODE 2: head-split transposed bf16 (v)
template <int MODE>
__global__ __launch_bounds__(256) void proj_gemm(const float* __restrict__ X,
                                                 const float* __restrict__ W,
                                                 float* __restrict__ Yf,
                                                 unsigned short* __restrict__ Y0,
                                                 unsigned short* __restrict__ Y1)
{
    __shared__ __align__(16) float As[16][132];
    __shared__ __align__(16) float Bs[16][132];
    const int t   = threadIdx.x;
    const int tm  = t & 15;         // row group
    const int tn  = t >> 4;         // col group 0..15
    const int row0 = blockIdx.x * 128;
    const int col0 = blockIdx.y * 128;
    const int lr  = t >> 1;         // staging row 0..127
    const int lc  = (t & 1) * 8;    // staging k-offset 0 or 8

    float acc[8][8];
#pragma unroll
    for (int i = 0; i < 8; ++i)
#pragma unroll
        for (int j = 0; j < 8; ++j) acc[i][j] = 0.f;

    // register double-buffered staging
    float4 xa, xb, wa, wb;
    const float* xp = X + (size_t)(row0 + lr) * DM_ + lc;
    const float* wp = W + (size_t)(col0 + lr) * DM_ + lc;
    xa = *(const float4*)(xp);     xb = *(const float4*)(xp + 4);
    wa = *(const float4*)(wp);     wb = *(const float4*)(wp + 4);

    for (int k0 = 0; k0 < DM_; k0 += 16) {
        __syncthreads();   // previous tile fully consumed
        As[lc + 0][lr] = xa.x; As[lc + 1][lr] = xa.y; As[lc + 2][lr] = xa.z; As[lc + 3][lr] = xa.w;
        As[lc + 4][lr] = xb.x; As[lc + 5][lr] = xb.y; As[lc + 6][lr] = xb.z; As[lc + 7][lr] = xb.w;
        Bs[lc + 0][lr] = wa.x; Bs[lc + 1][lr] = wa.y; Bs[lc + 2][lr] = wa.z; Bs[lc + 3][lr] = wa.w;
        Bs[lc + 4][lr] = wb.x; Bs[lc + 5][lr] = wb.y; Bs[lc + 6][lr] = wb.z; Bs[lc + 7][lr] = wb.w;
        __syncthreads();
        if (k0 + 16 < DM_) {
            xa = *(const float4*)(xp + k0 + 16);  xb = *(const float4*)(xp + k0 + 20);
            wa = *(const float4*)(wp + k0 + 16);  wb = *(const float4*)(wp + k0 + 20);
        }
#pragma unroll
        for (int kk = 0; kk < 16; ++kk) {
            float4 a0 = *(const float4*)&As[kk][tm * 4];
            float4 a1 = *(const float4*)&As[kk][64 + tm * 4];
            float4 b0 = *(const float4*)&Bs[kk][tn * 8];
            float4 b1 = *(const float4*)&Bs[kk][tn * 8 + 4];
            const float av[8] = {a0.x, a0.y, a0.z, a0.w, a1.x, a1.y, a1.z, a1.w};
            const float bv[8] = {b0.x, b0.y, b0.z, b0.w, b1.x, b1.y, b1.z, b1.w};
#pragma unroll
            for (int i = 0; i < 8; ++i)
#pragma unroll
                for (int j = 0; j < 8; ++j)
                    acc[i][j] = fmaf(av[i], bv[j], acc[i][j]);
        }
    }

    const int bidx = row0 >> 10;                 // 128-row tiles never straddle a batch
    const int hbase = blockIdx.y * 2 + (tn >> 3);  // head for MODE 0/2
    const int dbase = (tn & 7) * 8;                // dh base for MODE 0/2

    if constexpr (MODE == 1) {
#pragma unroll
        for (int i = 0; i < 8; ++i) {
            const int row = row0 + ((i < 4) ? (tm * 4 + i) : (64 + tm * 4 + i - 4));
            *(float4*)(Yf + (size_t)row * DM_ + col0 + tn * 8)     = make_float4(acc[i][0], acc[i][1], acc[i][2], acc[i][3]);
            *(float4*)(Yf + (size_t)row * DM_ + col0 + tn * 8 + 4) = make_float4(acc[i][4], acc[i][5], acc[i][6], acc[i][7]);
        }
    }
    if constexpr (MODE == 0) {
#pragma unroll
        for (int i = 0; i < 8; ++i) {
            const int row = row0 + ((i < 4) ? (tm * 4 + i) : (64 + tm * 4 + i - 4));
            const int l = row & 1023;
            const size_t base = (((size_t)bidx * H_ + hbase) * L_ + l) * DH_ + dbase;
#pragma unroll
            for (int jh = 0; jh < 2; ++jh) {
                ushort4 hi4, lo4;
                unsigned short* hp = (unsigned short*)&hi4;
                unsigned short* lp = (unsigned short*)&lo4;
#pragma unroll
                for (int j = 0; j < 4; ++j) {
                    const float y = acc[i][jh * 4 + j];
                    unsigned short hb = f2bf(y);
                    hp[j] = hb;
                    lp[j] = f2bf(y - bf2f(hb));
                }
                *(ushort4*)(Y0 + base + jh * 4) = hi4;
                *(ushort4*)(Y1 + base + jh * 4) = lo4;
            }
        }
    }
    if constexpr (MODE == 2) {
        // transposed store straight from registers: for each d, 4 consecutive l's -> ushort4
#pragma unroll
        for (int j = 0; j < 8; ++j) {
            const int d = dbase + j;
            const size_t cb = ((size_t)(bidx * H_ + hbase) * DH_ + d) * L_;
#pragma unroll
            for (int half = 0; half < 2; ++half) {
                const int l0 = (row0 & 1023) + half * 64 + tm * 4;
                ushort4 v4;
                unsigned short* vp = (unsigned short*)&v4;
#pragma unroll
                for (int i = 0; i < 4; ++i) vp[i] = f2bf(acc[half * 4 + i][j]);
                *(ushort4*)(Y0 + cb + l0) = v4;
            }
        }
    }
}

// ---------------- rel_k bf16 + rel_v transpose prep (known-good) ----------------
__global__ __launch_bounds__(256) void prep_rel(const float* __restrict__ rk,
                                                const float* __restrict__ rv,
                                                unsigned short* __restrict__ rk_hi,
                                                unsigned short* __restrict__ rv_t)
{
    const int idx = blockIdx.x * 256 + threadIdx.x;   // 0 .. 2048*64-1
    const int p = idx >> 6;
    const int d = idx & 63;
    float xk = (p < NP_) ? rk[(size_t)p * DH_ + d] : 0.f;
    rk_hi[idx] = f2bf(xk);
    float xv = (p < NP_) ? rv[(size_t)p * DH_ + d] : 0.f;
    rv_t[(size_t)d * NP2_ + p] = f2bf(xv);
}

// ---------------- MFMA Shaw attention v9 — R17/R18 body + XCD-aware block swizzle ----------------
// 1D grid 8192; bid -> (xcd = bid&7, slot = bid>>3); (b,h) group = (slot>>6)*8 + xcd, i-tile = slot&63.
// All 64 i-tile blocks of one (b,h) land consecutively on ONE XCD -> K/V/rel working set (~1.5 MB)
// concentrates in that XCD's 4 MB L2 (T1). Bijective since 8192 % 8 == 0.
__global__ __launch_bounds__(512, 4) void shaw_attn_mfma(
    const unsigned short* __restrict__ qh, const unsigned short* __restrict__ ql,
    const unsigned short* __restrict__ kh, const unsigned short* __restrict__ kl,
    const unsigned short* __restrict__ vt, const int* __restrict__ ridx,
    const unsigned short* __restrict__ rkh, const unsigned short* __restrict__ rvt,
    float* __restrict__ out)
{
    __shared__ __align__(16) unsigned char regionA[16 * PS_ * 2];  // 33,024 B: qrel8 -> Pu
    __shared__ __align__(16) unsigned char regionB[16 * HS_ * 4];  // 16,640 B: hist -> red
    __shared__ float pmax[16][8];
    __shared__ float psum[16][8];

    char*           qrel8 = (char*)regionA;              // [2048][16]
    unsigned short* Pu    = (unsigned short*)regionA;    // [16][PS_] (after qrel dead)
    float*          hist  = (float*)regionB;             // [16][HS_]
    float*          red   = (float*)regionB;             // [8][16][20] = 10,240 B (after hist dead)

    const int t    = threadIdx.x;
    const int w    = t >> 6;
    const int lane = t & 63;
    const int mrow = lane & 15;
    const int grp  = lane >> 4;

    // XCD-aware bijective remap
    const int bid  = blockIdx.x;
    const int xcd  = bid & 7;
    const int slot = bid >> 3;          // 0..1023
    const int g    = (slot >> 6) * 8 + xcd;   // 0..127 (b,h) group
    const int i0   = (slot & 63) * 16;
    const int b    = g >> 4;
    const int h    = g & 15;
    const size_t bh = (size_t)b * H_ + h;

    const unsigned short* qhp = qh + bh * (size_t)(L_ * DH_);
    const unsigned short* qlp = ql + bh * (size_t)(L_ * DH_);
    const unsigned short* khp = kh + bh * (size_t)(L_ * DH_);
    const unsigned short* klp = kl + bh * (size_t)(L_ * DH_);
    const unsigned short* vtp = vt + bh * (size_t)(DH_ * L_);

    // Q A-fragments
    bf16x8 qAh[2], qAl[2];
#pragma unroll
    for (int s = 0; s < 2; ++s) {
        const size_t off = (size_t)(i0 + mrow) * DH_ + s * 32 + grp * 8;
        qAh[s] = *(const bf16x8*)(qhp + off);
        qAl[s] = *(const bf16x8*)(qlp + off);
    }

    // ---- Phase 1: qrel int8 (x128) ----
    {
        const unsigned short* rb = rkh + (size_t)(w * 256 + mrow) * DH_ + grp * 8;
#pragma unroll 4
        for (int tt = 0; tt < 16; ++tt) {
            bf16x8 Bh0 = *(const bf16x8*)(rb + tt * 1024);
            bf16x8 Bh1 = *(const bf16x8*)(rb + tt * 1024 + 32);
            f32x4 c = {0.f, 0.f, 0.f, 0.f};
            c = __builtin_amdgcn_mfma_f32_16x16x32_bf16(qAh[0], Bh0, c, 0, 0, 0);
            c = __builtin_amdgcn_mfma_f32_16x16x32_bf16(qAh[1], Bh1, c, 0, 0, 0);
            const int pcol = (w * 16 + tt) * 16 + mrow;
            unsigned int pk = 0;
#pragma unroll
            for (int r = 0; r < 4; ++r) {
                int qi = (int)rintf(c[r] * 128.f);
                qi = qi > 127 ? 127 : (qi < -127 ? -127 : qi);
                pk |= ((unsigned int)(qi & 0xff)) << (8 * r);
            }
            *(unsigned int*)(qrel8 + pcol * 16 + grp * 4) = pk;
        }
    }
    __syncthreads();   // qrel ready

    // ---- Phase 2a: content scores (split-bf16 QK^T) ----
    float sc[8][4];
    {
        const unsigned short* kbh = khp + (size_t)(w * 128 + mrow) * DH_ + grp * 8;
        const unsigned short* kbl = klp + (size_t)(w * 128 + mrow) * DH_ + grp * 8;
#pragma unroll 2
        for (int tt = 0; tt < 8; ++tt) {
            bf16x8 Bh0 = *(const bf16x8*)(kbh + tt * 1024);
            bf16x8 Bh1 = *(const bf16x8*)(kbh + tt * 1024 + 32);
            bf16x8 Bl0 = *(const bf16x8*)(kbl + tt * 1024);
            bf16x8 Bl1 = *(const bf16x8*)(kbl + tt * 1024 + 32);
            f32x4 c = {0.f, 0.f, 0.f, 0.f};
            c = __builtin_amdgcn_mfma_f32_16x16x32_bf16(qAh[0], Bh0, c, 0, 0, 0);
            c = __builtin_amdgcn_mfma_f32_16x16x32_bf16(qAh[1], Bh1, c, 0, 0, 0);
            c = __builtin_amdgcn_mfma_f32_16x16x32_bf16(qAh[0], Bl0, c, 0, 0, 0);
            c = __builtin_amdgcn_mfma_f32_16x16x32_bf16(qAh[1], Bl1, c, 0, 0, 0);
            c = __builtin_amdgcn_mfma_f32_16x16x32_bf16(qAl[0], Bh0, c, 0, 0, 0);
            c = __builtin_amdgcn_mfma_f32_16x16x32_bf16(qAl[1], Bh1, c, 0, 0, 0);
#pragma unroll
            for (int r = 0; r < 4; ++r) sc[tt][r] = c[r] * SCALE_;
        }
    }

    // ---- Phase 2b: rel gather ----
#pragma unroll
    for (int tt = 0; tt < 8; ++tt) {
        const int jcol = (w * 8 + tt) * 16 + mrow;
#pragma unroll
        for (int r = 0; r < 4; ++r) {
            const int pidx = ridx[(size_t)(i0 + grp * 4 + r) * L_ + jcol];
            sc[tt][r] = fmaf((float)qrel8[pidx * 16 + grp * 4 + r], SCALE_ / 128.f, sc[tt][r]);
        }
    }

    // ---- Phase 3: softmax ----
    float mx[4];
#pragma unroll
    for (int r = 0; r < 4; ++r) {
        float m = sc[0][r];
#pragma unroll
        for (int tt = 1; tt < 8; ++tt) m = fmaxf(m, sc[tt][r]);
#pragma unroll
        for (int off = 1; off < 16; off <<= 1) m = fmaxf(m, __shfl_xor(m, off));
        mx[r] = m;
    }
    {
        const float wv0 = (mrow == 0) ? mx[0] : (mrow == 1) ? mx[1] : (mrow == 2) ? mx[2] : mx[3];
        if (mrow < 4) pmax[grp * 4 + mrow][w] = wv0;
    }
    __syncthreads();   // pmax ready; last qrel8 read done before Pu overwrite below

    float gm[4];
#pragma unroll
    for (int r = 0; r < 4; ++r) {
        const int rr = grp * 4 + r;
        float m = pmax[rr][0];
#pragma unroll
        for (int u = 1; u < 8; ++u) m = fmaxf(m, pmax[rr][u]);
        gm[r] = m;
    }
    float sm[4] = {0.f, 0.f, 0.f, 0.f};
#pragma unroll
    for (int tt = 0; tt < 8; ++tt) {
        const int jcol = (w * 8 + tt) * 16 + mrow;
#pragma unroll
        for (int r = 0; r < 4; ++r) {
            const float e = __expf(sc[tt][r] - gm[r]);
            sm[r] += e;
            Pu[(grp * 4 + r) * PS_ + jcol] = f2bf(e);   // into dead qrel region
        }
    }
#pragma unroll
    for (int r = 0; r < 4; ++r) {
#pragma unroll
        for (int off = 1; off < 16; off <<= 1) sm[r] += __shfl_xor(sm[r], off);
    }
    {
        const float sv0 = (mrow == 0) ? sm[0] : (mrow == 1) ? sm[1] : (mrow == 2) ? sm[2] : sm[3];
        if (mrow < 4) psum[grp * 4 + mrow][w] = sv0;
    }
    __syncthreads();   // Pu + psum ready

    // ---- Phase 4: O1 = P @ V (wave task (n, khalf)) ----
    const int n = w & 3;
    const int khalf = w >> 2;
    f32x4 acc = {0.f, 0.f, 0.f, 0.f};
    {
        const unsigned short* vcol = vtp + (size_t)(n * 16 + mrow) * L_ + khalf * 512 + grp * 8;
#pragma unroll 4
        for (int s = 0; s < 16; ++s) {
            bf16x8 a  = *(const bf16x8*)(Pu + mrow * PS_ + khalf * 512 + s * 32 + grp * 8);
            bf16x8 bb = *(const bf16x8*)(vcol + s * 32);
            acc = __builtin_amdgcn_mfma_f32_16x16x32_bf16(a, bb, acc, 0, 0, 0);
        }
    }

    // ---- Phase 5: 8 hist passes of 256 positions (hist in its own region; Pu stays live) ----
    for (int pass = 0; pass < 8; ++pass) {
        {
            float4* h4 = (float4*)hist;
            const float4 z4 = make_float4(0.f, 0.f, 0.f, 0.f);
            for (int z = t; z < (16 * HS_) / 4; z += 512) h4[z] = z4;
        }
        __syncthreads();
        // scatter: each thread scatters its own 32 (row, j) P-entries (LDS reads of own writes)
#pragma unroll
        for (int tt = 0; tt < 8; ++tt) {
            const int jcol = (w * 8 + tt) * 16 + mrow;
#pragma unroll
            for (int r = 0; r < 4; ++r) {
                const int rr = grp * 4 + r;
                const int pidx = ridx[(size_t)(i0 + rr) * L_ + jcol];
                if ((pidx >> 8) == pass)
                    atomicAdd(&hist[rr * HS_ + (pidx & 255)], bf2f(Pu[rr * PS_ + jcol]));
            }
        }
        __syncthreads();
        // O2 += hist(256-wide) @ rel_v: per (n, khalf) wave, 4 k-tiles of 32
        const unsigned short* rvcol =
            rvt + (size_t)(n * 16 + mrow) * NP2_ + pass * 256 + khalf * 128 + grp * 8;
#pragma unroll
        for (int s = 0; s < 4; ++s) {
            const int kb = khalf * 128 + s * 32;
            const f32x4* hp = (const f32x4*)&hist[mrow * HS_ + kb + grp * 8];
            f32x4 h0 = hp[0], h1 = hp[1];
            bf16x8 a;
#pragma unroll
            for (int e = 0; e < 4; ++e) { a[e] = (short)f2bf(h0[e]); a[e + 4] = (short)f2bf(h1[e]); }
            bf16x8 bb = *(const bf16x8*)(rvcol + s * 32);
            acc = __builtin_amdgcn_mfma_f32_16x16x32_bf16(a, bb, acc, 0, 0, 0);
        }
        __syncthreads();   // readers done -> next zero / red alias safe
    }

    // ---- Phase 6: khalf reduce + normalize + fp32 store ----
#pragma unroll
    for (int r = 0; r < 4; ++r) red[w * 320 + (grp * 4 + r) * 20 + mrow] = acc[r];
    __syncthreads();
    if (w < 4) {
#pragma unroll
        for (int r = 0; r < 4; ++r) {
            const int rr = grp * 4 + r;
            float o = red[w * 320 + rr * 20 + mrow] + red[(w + 4) * 320 + rr * 20 + mrow];
            float ssum = 0.f;
#pragma unroll
            for (int u = 0; u < 8; ++u) ssum += psum[rr][u];
            out[((size_t)b * L_ + i0 + rr) * DM_ + h * DH_ + w * 16 + mrow] = o / ssum;
        }
    }
}

extern "C" void kernel_launch(void* const* d_in, const int* in_sizes, int n_in,
                              void* d_out, int out_size, void* d_ws, size_t ws_size,
                              hipStream_t stream)
{
    const float* x    = (const float*)d_in[0];
    const int*   ridx = (const int*)  d_in[1];
    const float* Wq   = (const float*)d_in[2];
    const float* Wk   = (const float*)d_in[3];
    const float* Wv   = (const float*)d_in[4];
    const float* Wo   = (const float*)d_in[5];
    const float* rk   = (const float*)d_in[6];
    const float* rv   = (const float*)d_in[7];
    float* out = (float*)d_out;

    // R8/R14/R17's proven workspace plan: 117,964,800 B; every buffer single-writer.
    const size_t NQ = (size_t)B_ * H_ * L_ * DH_;      // 8,388,608
    float* attn = (float*)d_ws;                        // NQ f32
    unsigned short* u = (unsigned short*)(attn + NQ);
    unsigned short* qh = u;            u += NQ;
    unsigned short* ql = u;            u += NQ;
    unsigned short* kh = u;            u += NQ;
    unsigned short* kl = u;            u += NQ;
    unsigned short* vt = u;            u += NQ;
    unsigned short* rkh = u;           u += (size_t)NP2_ * DH_;
    unsigned short* rvt = u;           u += (size_t)NP2_ * DH_;

    dim3 gthr(256);
    dim3 ggrid((B_ * L_) / 128, DM_ / 128);   // (64, 8) — 128x128 tiles

    prep_rel<<<dim3((NP2_ * DH_) / 256), gthr, 0, stream>>>(rk, rv, rkh, rvt);
    proj_gemm<0><<<ggrid, gthr, 0, stream>>>(x, Wq, nullptr, qh, ql);
    proj_gemm<0><<<ggrid, gthr, 0, stream>>>(x, Wk, nullptr, kh, kl);
    proj_gemm<2><<<ggrid, gthr, 0, stream>>>(x, Wv, nullptr, vt, nullptr);

    shaw_attn_mfma<<<dim3(8192), dim3(512), 0, stream>>>(
        qh, ql, kh, kl, vt, ridx, rkh, rvt, attn);

    proj_gemm<1><<<ggrid, gthr, 0, stream>>>(attn, Wo, out, nullptr, nullptr);
}